// Round 1
// baseline (272.108 us; speedup 1.0000x reference)
//
#include <hip/hip_runtime.h>

#define EPS 1e-5f

// LDS layout (float offsets)
#define OFF_RS     0       // [8][64] row sums
#define OFF_CS     512     // [8][64] col sums
#define OFF_SH     1024    // [8][64] sigmoid row gate
#define OFF_SW     1536    // [8][64] sigmoid col gate
#define OFF_SSUM   2048    // [8] channel total sums
#define OFF_MU     2056    // [8]
#define OFF_RSTD   2064    // [8]
#define OFF_M2     2072    // [8] x21 logits
#define OFF_X21    2080    // [8]
#define OFF_X11    2088    // [8]
#define OFF_ALPHA  2096    // [8]
#define OFF_KC     2104    // [1] constant part of y
#define OFF_GSUM   2112    // [8] gated sum
#define OFF_GSSQ   2120    // [8] gated sumsq
#define OFF_WEFF   2128    // [72] effective 1-out-channel filter
#define OFF_GX     2560    // [8][66][64], storage row = i+1 (rows 0,65 zero pad)
#define SMEM_FLOATS (2560 + 8*66*64)
#define SMEM_BYTES  (SMEM_FLOATS * 4)

// XOR swizzle: logical column j at storage row s -> physical column.
// Spreads column-wise (stride-256B) accesses across banks.
__device__ __forceinline__ int physcol(int j, int s) {
  return (((j >> 2) ^ (s & 15)) << 2) | (j & 3);
}

__launch_bounds__(512, 2)
__global__ void fused_all(const float* __restrict__ x,
                          const float* __restrict__ w1,
                          const float* __restrict__ b1,
                          const float* __restrict__ w3,
                          const float* __restrict__ b3,
                          const float* __restrict__ gn_w,
                          const float* __restrict__ gn_b,
                          float* __restrict__ out)
{
  extern __shared__ float sm[];
  const int t    = threadIdx.x;
  const int lane = t & 63;
  const int wv   = t >> 6;          // wave id 0..7
  const int g    = blockIdx.x;      // group id 0..1023

  const float* xg = x  + (size_t)g * 32768;
  float*       og = out + (size_t)g * 32768;
  float* gxs = sm + OFF_GX;

  // ---- Ph0: zero vertical pad rows (storage rows 0 and 65 per channel) ----
  {
    int c = t >> 6;                                  // 0..7
    gxs[c*4224 + 0*64  + lane] = 0.f;
    gxs[c*4224 + 65*64 + lane] = 0.f;
  }

  // ---- Ph1: load gx -> LDS (batched float4, swizzled columns) ----
  {
    const float4* xg4 = (const float4*)xg;
    float4 ld[16];
#pragma unroll
    for (int k = 0; k < 16; ++k) ld[k] = xg4[t + k*512];
#pragma unroll
    for (int k = 0; k < 16; ++k) {
      int f  = t + k*512;            // float4 index 0..8191
      int c  = f >> 10;
      int r  = f & 1023;
      int i  = r >> 4;
      int s  = i + 1;                // storage row
      int jq = (r & 15) ^ (s & 15);  // swizzled float4 group
      *(float4*)&gxs[c*4224 + s*64 + (jq << 2)] = ld[k];
    }
  }
  __syncthreads();

  // ---- Ph2: row sums rs[c][i] and col sums cs[c][j] ----
  {
    int c = t >> 6, i = lane, s = i + 1;
    const float* rb = &gxs[c*4224 + s*64];
    float acc = 0.f;
#pragma unroll
    for (int k = 0; k < 16; ++k) {
      int jq = k ^ (s & 15);
      float4 v = *(const float4*)&rb[jq << 2];
      acc += (v.x + v.y) + (v.z + v.w);
    }
    sm[OFF_RS + c*64 + i] = acc;
  }
  {
    int c = t >> 6, j = lane;
    float acc = 0.f;
    for (int i = 0; i < 64; ++i) {
      int s = i + 1;
      acc += gxs[c*4224 + s*64 + physcol(j, s)];
    }
    sm[OFF_CS + c*64 + j] = acc;
  }
  __syncthreads();

  // ---- Ph3a: gates sh/sw (8x8 matvec + sigmoid); channel totals S ----
  {
    int o = t >> 6, i = lane;
    float a1 = b1[o], a2 = b1[o];
#pragma unroll
    for (int c = 0; c < 8; ++c) {
      float wv1 = w1[o*8 + c];
      a1 = fmaf(wv1, sm[OFF_RS + c*64 + i] * (1.f/64.f), a1);
      a2 = fmaf(wv1, sm[OFF_CS + c*64 + i] * (1.f/64.f), a2);
    }
    sm[OFF_SH + o*64 + i] = 1.f / (1.f + __expf(-a1));
    sm[OFF_SW + o*64 + i] = 1.f / (1.f + __expf(-a2));
  }
  if (t < 8) {
    float S = 0.f;
    for (int i = 0; i < 64; ++i) S += sm[OFF_RS + t*64 + i];
    sm[OFF_SSUM + t] = S;
  }
  __syncthreads();

  // ---- Ph3b: gated = gx*sh*sw stats; wave wv owns channel wv ----
  {
    const int c  = wv;
    const int jq = lane & 15;
    float p1 = 0.f, p2 = 0.f;
    const float4 swv = *(const float4*)&sm[OFF_SW + c*64 + (jq << 2)];
#pragma unroll
    for (int k = 0; k < 16; ++k) {
      int i = (lane >> 4) + (k << 2);
      int s = i + 1;
      const float4 v = *(const float4*)&gxs[c*4224 + s*64 + ((jq ^ (s & 15)) << 2)];
      float shv = sm[OFF_SH + c*64 + i];
      float g0 = v.x * shv * swv.x;
      float g1 = v.y * shv * swv.y;
      float g2 = v.z * shv * swv.z;
      float g3 = v.w * shv * swv.w;
      p1 += (g0 + g1) + (g2 + g3);
      p2 += (g0*g0 + g1*g1) + (g2*g2 + g3*g3);
    }
#pragma unroll
    for (int off = 32; off; off >>= 1) {
      p1 += __shfl_xor(p1, off, 64);
      p2 += __shfl_xor(p2, off, 64);
    }
    if (lane == 0) { sm[OFF_GSUM + c] = p1; sm[OFF_GSSQ + c] = p2; }
  }
  __syncthreads();

  // ---- Ph3c: mu/rstd; x21 logits via shifted-sum closed form ----
  if (t < 8) {
    float mu  = sm[OFF_GSUM + t] * (1.f/4096.f);
    float var = sm[OFF_GSSQ + t] * (1.f/4096.f) - mu*mu;
    sm[OFF_MU + t]   = mu;
    sm[OFF_RSTD + t] = rsqrtf(var + EPS);
  } else if (t >= 64 && t < 72) {
    int o = t - 64;
    float acc = 0.f;
    for (int ic = 0; ic < 8; ++ic) {
      float S   = sm[OFF_SSUM + ic];
      float r0  = sm[OFF_RS + ic*64 + 0];
      float r63 = sm[OFF_RS + ic*64 + 63];
      float c0  = sm[OFF_CS + ic*64 + 0];
      float c63 = sm[OFF_CS + ic*64 + 63];
      float g00   = gxs[ic*4224 + 1*64  + physcol(0, 1)];
      float g063  = gxs[ic*4224 + 1*64  + physcol(63, 1)];
      float g630  = gxs[ic*4224 + 64*64 + physcol(0, 64)];
      float g6363 = gxs[ic*4224 + 64*64 + physcol(63, 64)];
      const float* w3p = w3 + (o*8 + ic)*9;
#pragma unroll
      for (int kh = 0; kh < 3; ++kh) {
        // input row shift a = kh-1: a=-1 excludes row 63, a=+1 excludes row 0
        float rex = (kh == 0) ? r63 : (kh == 2) ? r0 : 0.f;
#pragma unroll
        for (int kw = 0; kw < 3; ++kw) {
          float cex = (kw == 0) ? c63 : (kw == 2) ? c0 : 0.f;
          float corner = 0.f;
          if      (kh == 0 && kw == 0) corner = g6363;
          else if (kh == 0 && kw == 2) corner = g630;
          else if (kh == 2 && kw == 0) corner = g063;
          else if (kh == 2 && kw == 2) corner = g00;
          acc = fmaf(w3p[kh*3 + kw], (S - rex - cex) + corner, acc);
        }
      }
    }
    sm[OFF_M2 + o] = b3[o] + acc * (1.f/4096.f);
  }
  __syncthreads();

  // ---- Ph3d: softmaxes + scalar constants (thread 0) ----
  if (t == 0) {
    float e[8];
    float m = sm[OFF_M2];
    for (int c = 1; c < 8; ++c) m = fmaxf(m, sm[OFF_M2 + c]);
    float ssum = 0.f;
    for (int c = 0; c < 8; ++c) { e[c] = __expf(sm[OFF_M2 + c] - m); ssum += e[c]; }
    float kc = 0.f;
    for (int c = 0; c < 8; ++c) {
      float x21 = e[c] / ssum;
      sm[OFF_X21 + c]   = x21;
      sm[OFF_ALPHA + c] = x21 * gn_w[c] * sm[OFF_RSTD + c];
      kc += x21 * (gn_b[c] - gn_w[c] * sm[OFF_RSTD + c] * sm[OFF_MU + c]);
    }
    // x11 = softmax(gn_b)  (x1 channel means are exactly gn_b)
    float m1 = gn_b[0];
    for (int c = 1; c < 8; ++c) m1 = fmaxf(m1, gn_b[c]);
    float s1 = 0.f;
    for (int c = 0; c < 8; ++c) { e[c] = __expf(gn_b[c] - m1); s1 += e[c]; }
    for (int c = 0; c < 8; ++c) {
      float x11 = e[c] / s1;
      sm[OFF_X11 + c] = x11;
      kc = fmaf(x11, b3[c], kc);   // fold sum(x11*b3) into constant
    }
    sm[OFF_KC] = kc;
  }
  __syncthreads();

  // ---- Ph3e: effective filter weff[ic][kh][kw] = sum_o x11[o]*w3[o][ic][kh][kw] ----
  if (t < 72) {
    float acc = 0.f;
#pragma unroll
    for (int o = 0; o < 8; ++o) acc = fmaf(sm[OFF_X11 + o], w3[o*72 + t], acc);
    sm[OFF_WEFF + t] = acc;
  }
  __syncthreads();

  // ---- Ph4: fused conv + gating + sigmoid + output ----
  {
    const int sub = lane >> 4;     // row-within-quad
    const int lx  = lane & 15;     // float4 group along j
    const int j4  = lx << 2;
    float wf[72];
#pragma unroll
    for (int q = 0; q < 72; ++q) wf[q] = sm[OFF_WEFF + q];
    float al[8];
#pragma unroll
    for (int c = 0; c < 8; ++c) al[c] = sm[OFF_ALPHA + c];
    const float kconst = sm[OFF_KC];

#pragma unroll
    for (int rr = 0; rr < 2; ++rr) {
      const int i = (wv << 3) + (rr << 2) + sub;   // output row 0..63
      float y0 = kconst, y1 = kconst, y2 = kconst, y3 = kconst;
      float4 cen[8];
#pragma unroll
      for (int ic = 0; ic < 8; ++ic) {
        const float* cb = &gxs[ic*4224];
#pragma unroll
        for (int kh = 0; kh < 3; ++kh) {
          const int s = i + kh;                    // storage row 0..65 (pads valid)
          const float* rbase = cb + s*64;
          const int key = s & 15;
          float4 c4 = *(const float4*)(rbase + ((lx ^ key) << 2));
          float lv = (lx == 0)  ? 0.f : rbase[(((lx-1) ^ key) << 2) + 3];
          float rv = (lx == 15) ? 0.f : rbase[(((lx+1) ^ key) << 2)];
          const float w0  = wf[ic*9 + kh*3 + 0];
          const float w1v = wf[ic*9 + kh*3 + 1];
          const float w2  = wf[ic*9 + kh*3 + 2];
          y0 = fmaf(w0, lv,   fmaf(w1v, c4.x, fmaf(w2, c4.y, y0)));
          y1 = fmaf(w0, c4.x, fmaf(w1v, c4.y, fmaf(w2, c4.z, y1)));
          y2 = fmaf(w0, c4.y, fmaf(w1v, c4.z, fmaf(w2, c4.w, y2)));
          y3 = fmaf(w0, c4.z, fmaf(w1v, c4.w, fmaf(w2, rv,  y3)));
          if (kh == 1) cen[ic] = c4;               // center row = gx[ic][i][j4..]
        }
      }
#pragma unroll
      for (int c = 0; c < 8; ++c) {
        float sgate = al[c] * sm[OFF_SH + c*64 + i];
        const float4 swv = *(const float4*)&sm[OFF_SW + c*64 + j4];
        y0 = fmaf(sgate * swv.x, cen[c].x, y0);
        y1 = fmaf(sgate * swv.y, cen[c].y, y1);
        y2 = fmaf(sgate * swv.z, cen[c].z, y2);
        y3 = fmaf(sgate * swv.w, cen[c].w, y3);
      }
      const float wg0 = 1.f / (1.f + __expf(-y0));
      const float wg1 = 1.f / (1.f + __expf(-y1));
      const float wg2 = 1.f / (1.f + __expf(-y2));
      const float wg3 = 1.f / (1.f + __expf(-y3));
#pragma unroll
      for (int c = 0; c < 8; ++c) {
        float4 o4;
        o4.x = cen[c].x * wg0;
        o4.y = cen[c].y * wg1;
        o4.z = cen[c].z * wg2;
        o4.w = cen[c].w * wg3;
        *(float4*)&og[c*4096 + i*64 + j4] = o4;
      }
    }
  }
}

extern "C" void kernel_launch(void* const* d_in, const int* in_sizes, int n_in,
                              void* d_out, int out_size, void* d_ws, size_t ws_size,
                              hipStream_t stream) {
  (void)in_sizes; (void)n_in; (void)d_ws; (void)ws_size; (void)out_size;
  const float* x    = (const float*)d_in[0];
  const float* w1   = (const float*)d_in[1];
  const float* b1   = (const float*)d_in[2];
  const float* w3   = (const float*)d_in[3];
  const float* b3   = (const float*)d_in[4];
  const float* gn_w = (const float*)d_in[5];
  const float* gn_b = (const float*)d_in[6];
  float* out = (float*)d_out;

  // >64 KiB dynamic LDS needs the opt-in attribute (idempotent, capture-safe)
  hipFuncSetAttribute((const void*)fused_all,
                      hipFuncAttributeMaxDynamicSharedMemorySize, SMEM_BYTES);
  fused_all<<<1024, 512, SMEM_BYTES, stream>>>(x, w1, b1, w3, b3, gn_w, gn_b, out);
}